// Round 13
// baseline (255.140 us; speedup 1.0000x reference)
//
#include <hip/hip_runtime.h>
#include <hip/hip_bf16.h>

#define NN 100000
#define NE 800000
#define HIDDEN 128
#define NED (2 * NE)            // edge-directions: [0,NE)=fwd(by src), [NE,2NE)=bwd(by dst)
#define BKN 64                  // nodes per bucket (bucket covers BOTH directions)
#define NBF 1563                // ceil(NN/BKN)
#define BCAP 2048               // slots per bucket (mean 1024, +32 sigma)
#define PS 7                    // buckets per thread in scatter scan (7*256>=1563)
#define CHUNK 8192              // edges per scatter block (67KB LDS -> 2 blocks/CU)
#define PBLK ((NED + CHUNK - 1) / CHUNK)   // 196

typedef __attribute__((ext_vector_type(8))) short bf16x8;
typedef __attribute__((ext_vector_type(4))) short bf16x4;
typedef __attribute__((ext_vector_type(4))) float f32x4;

__device__ __forceinline__ short f2bf(float f) {
  union { float f; unsigned u; } x; x.f = f;
  unsigned r = x.u + 0x7fffu + ((x.u >> 16) & 1u);   // RNE
  return (short)(r >> 16);
}
__device__ __forceinline__ float bf2f(short s) {
  union { unsigned u; float f; } x;
  x.u = ((unsigned)(unsigned short)s) << 16;
  return x.f;
}

// ---- 1. convert h (12500 blocks) + weights (192 blocks) in ONE kernel ----
// weights order: [0]=Ws_w, [1]=W_w, [2]=Wt_w
__global__ __launch_bounds__(256) void convert_all(
    const float* __restrict__ h, const float* __restrict__ m0,
    const float* __restrict__ m1, const float* __restrict__ m2,
    short* __restrict__ h_bf, short* __restrict__ Wbf) {
  int blk = blockIdx.x;
  int tid = threadIdx.x;
  if (blk < 12500) {
    int i = blk * 256 + tid;                 // 3.2M exact (NN*HIDDEN/4)
    f32x4 v = *(const f32x4*)(h + (size_t)i * 4);
    bf16x4 o;
#pragma unroll
    for (int j = 0; j < 4; j++) o[j] = f2bf(v[j]);
    *(bf16x4*)(h_bf + (size_t)i * 4) = o;
  } else {
    int i = (blk - 12500) * 256 + tid;       // [0, 3*16384) exact
    int m = i >> 14, j = i & 16383;
    const float* s = (m == 0) ? m0 : (m == 1) ? m1 : m2;
    Wbf[i] = f2bf(s[j]);
  }
}

// ---- 2. blocked LDS-aggregated scatter into capacity-allocated regions ----
// LDS count -> LDS scan -> ONE returning atomic per non-empty bucket per
// block -> LDS-staged scatter -> coalesced run sweep.
// ELP item: (dir<<23)|(tl<<17)|nbr; vn=pv>>17. gcur[b] ends as bucket count.
__global__ __launch_bounds__(256) void edge_scatter(
    const int* __restrict__ esrc, const int* __restrict__ edst,
    int* __restrict__ gcur, unsigned* __restrict__ ELP) {
  __shared__ int lcur[NBF];       // counts, then mutable scatter cursors
  __shared__ int loff[NBF];       // block-local exclusive offsets (kept intact)
  __shared__ int gbase[NBF];      // claimed global run starts
  __shared__ int psum[256];
  __shared__ unsigned buf[CHUNK]; // 32 KB staging
  __shared__ unsigned short bidA[CHUNK];  // 16 KB bucket-id per slot
  int tid = threadIdx.x;
  for (int i = tid; i < NBF; i += 256) lcur[i] = 0;
  __syncthreads();
  int base = blockIdx.x * CHUNK;
  int nit = min(CHUNK, NED - base);
  // pass 1: local count
  for (int k = tid; k < nit; k += 256) {
    int ed = base + k;
    int b = (ed < NE) ? (esrc[ed] >> 6) : (edst[ed - NE] >> 6);
    atomicAdd(&lcur[b], 1);
  }
  __syncthreads();
  // local exclusive scan (PS buckets per thread)
  int s = 0;
  int lo0 = tid * PS, hi0 = min(NBF, tid * PS + PS);
  for (int j = lo0; j < hi0; j++) s += lcur[j];
  psum[tid] = s;
  __syncthreads();
  for (int off = 1; off < 256; off <<= 1) {
    int x = psum[tid];
    int add = (tid >= off) ? psum[tid - off] : 0;
    __syncthreads();
    psum[tid] = x + add;
    __syncthreads();
  }
  int run = psum[tid] - s;
  for (int j = lo0; j < hi0; j++) { loff[j] = run; run += lcur[j]; }
  __syncthreads();
  // claim global runs (one returning atomic per non-empty bucket) + cursors
  for (int b = tid; b < NBF; b += 256) {
    int c = lcur[b];
    if (c) gbase[b] = atomicAdd(gcur + b, c);
    lcur[b] = loff[b];
  }
  __syncthreads();
  // pass 2: scatter into LDS staging, record bucket id per slot
  for (int k = tid; k < nit; k += 256) {
    int ed = base + k;
    int b, tl, nbr, dir;
    if (ed < NE) { int tg = esrc[ed]; nbr = edst[ed]; b = tg >> 6; tl = tg & 63; dir = 0; }
    else { int e2 = ed - NE; int tg = edst[e2]; nbr = esrc[e2]; b = tg >> 6; tl = tg & 63; dir = 1; }
    int slot = atomicAdd(&lcur[b], 1);
    buf[slot] = ((unsigned)dir << 23) | ((unsigned)tl << 17) | (unsigned)nbr;
    bidA[slot] = (unsigned short)b;
  }
  __syncthreads();
  // sweep: consecutive lanes -> consecutive slots -> bucket-contiguous runs
  for (int i = tid; i < nit; i += 256) {
    int b = bidA[i];
    int dst = gbase[b] + (i - loff[b]);
    if (dst < BCAP) ELP[(size_t)b * BCAP + dst] = buf[i];
  }
}

// ---- 3. FUSED gather + GEMM per 64-node range, TWO-PASS agg tile ----
// r12 structure (best: 99.9us, 50% occ) with the acc spill fixed: the
// gather-half LAMBDA held acc[4] across its call and regalloc spilled it
// (WRITE_SIZE 50->81MB, rule #20 family). Here the gather is macro-inlined
// (flat function body) and acc is four NAMED f32x4s -> registers.
// B1(gather fwd)->C1(acc=Ws*h+W*aggF)->B2(gather bwd)->C2(acc+=Wt*aggB).
// LDS 42.5KB -> 3 blocks/CU; launch_bounds(512,6) caps VGPR at 85.
#define ACC8(V) { a0f+=bf2f((V)[0]); a1f+=bf2f((V)[1]); a2f+=bf2f((V)[2]); a3f+=bf2f((V)[3]); \
                  a4f+=bf2f((V)[4]); a5f+=bf2f((V)[5]); a6f+=bf2f((V)[6]); a7f+=bf2f((V)[7]); }
#define MACC8(M,V) { a0f=fmaf(M,bf2f((V)[0]),a0f); a1f=fmaf(M,bf2f((V)[1]),a1f); \
                     a2f=fmaf(M,bf2f((V)[2]),a2f); a3f=fmaf(M,bf2f((V)[3]),a3f); \
                     a4f=fmaf(M,bf2f((V)[4]),a4f); a5f=fmaf(M,bf2f((V)[5]),a5f); \
                     a6f=fmaf(M,bf2f((V)[6]),a6f); a7f=fmaf(M,bf2f((V)[7]),a7f); }
// gather 2 vns of one direction into swizzled At (flat inline, no lambda)
#define GATHER_HALF(VBASE) \
  _Pragma("unroll") \
  for (int t = 0; t < 2; t++) { \
    int nd = (VBASE) + qw * 2 + t; \
    int b0 = pfx[nd]; \
    int deg = cnt[nd]; \
    int a0 = b0 - deg; \
    float a0f = 0.f, a1f = 0.f, a2f = 0.f, a3f = 0.f; \
    float a4f = 0.f, a5f = 0.f, a6f = 0.f, a7f = 0.f; \
    if (deg > 0) { \
      int lastp = b0 - 1; \
      int i0 = sorted[a0]; \
      int i1 = sorted[min(a0 + 1, lastp)]; \
      int i2 = sorted[min(a0 + 2, lastp)]; \
      int i3 = sorted[min(a0 + 3, lastp)]; \
      bf16x8 v0 = *(const bf16x8*)(hb + (size_t)i0 * HIDDEN); \
      bf16x8 v1 = *(const bf16x8*)(hb + (size_t)i1 * HIDDEN); \
      bf16x8 v2 = *(const bf16x8*)(hb + (size_t)i2 * HIDDEN); \
      bf16x8 v3 = *(const bf16x8*)(hb + (size_t)i3 * HIDDEN); \
      int j = a0; \
      int ni0 = sorted[min(j + 4, lastp)]; \
      int ni1 = sorted[min(j + 5, lastp)]; \
      int ni2 = sorted[min(j + 6, lastp)]; \
      int ni3 = sorted[min(j + 7, lastp)]; \
      while (j + 4 <= b0) { \
        ACC8(v0); v0 = *(const bf16x8*)(hb + (size_t)ni0 * HIDDEN); \
        ACC8(v1); v1 = *(const bf16x8*)(hb + (size_t)ni1 * HIDDEN); \
        ACC8(v2); v2 = *(const bf16x8*)(hb + (size_t)ni2 * HIDDEN); \
        ACC8(v3); v3 = *(const bf16x8*)(hb + (size_t)ni3 * HIDDEN); \
        j += 4; \
        ni0 = sorted[min(j + 4, lastp)]; \
        ni1 = sorted[min(j + 5, lastp)]; \
        ni2 = sorted[min(j + 6, lastp)]; \
        ni3 = sorted[min(j + 7, lastp)]; \
      } \
      int rrem = b0 - j; \
      float m1 = (rrem > 0) ? 1.f : 0.f; \
      float m2 = (rrem > 1) ? 1.f : 0.f; \
      float m3 = (rrem > 2) ? 1.f : 0.f; \
      MACC8(m1, v0); MACC8(m2, v1); MACC8(m3, v2); \
    } \
    short* dst = At + (nd & 63) * 128 + ((q ^ (nd & 7)) * 8); \
    bf16x8 o; \
    o[0] = f2bf(a0f); o[1] = f2bf(a1f); o[2] = f2bf(a2f); o[3] = f2bf(a3f); \
    o[4] = f2bf(a4f); o[5] = f2bf(a5f); o[6] = f2bf(a6f); o[7] = f2bf(a7f); \
    *(bf16x8*)dst = o; \
  }
// one 16-row group of C1: 4 Ws*h + 4 W*aggF MFMAs into ACCV
#define C1_STEP(G, ACCV) { \
  int rl = (G) * 16 + m16; \
  const short* hrow = Ht + rl * 128; \
  const short* arow = At + rl * 128; \
  _Pragma("unroll") \
  for (int t = 0; t < 4; t++) { \
    int pc = (kq + 4 * t) ^ key; \
    bf16x8 hv = *(const bf16x8*)(hrow + pc * 8); \
    ACCV = __builtin_amdgcn_mfma_f32_16x16x32_bf16(wfS[t], hv, ACCV, 0, 0, 0); \
  } \
  _Pragma("unroll") \
  for (int t = 0; t < 4; t++) { \
    int pc = (kq + 4 * t) ^ key; \
    bf16x8 av = *(const bf16x8*)(arow + pc * 8); \
    ACCV = __builtin_amdgcn_mfma_f32_16x16x32_bf16(wfF[t], av, ACCV, 0, 0, 0); \
  } }
// one 16-row group of C2: 4 Wt*aggB MFMAs + epilogue store
#define C2_STEP(G, ACCV) { \
  int rl = (G) * 16 + m16; \
  const short* arow = At + rl * 128; \
  _Pragma("unroll") \
  for (int t = 0; t < 4; t++) { \
    int pc = (kq + 4 * t) ^ key; \
    bf16x8 av = *(const bf16x8*)(arow + pc * 8); \
    ACCV = __builtin_amdgcn_mfma_f32_16x16x32_bf16(wfT[t], av, ACCV, 0, 0, 0); \
  } \
  int r = node0 + rl; \
  if (r < NN) { \
    float dF = (float)cnt[rl]; \
    float dB = (float)cnt[64 + rl]; \
    f32x4 vv; \
    _Pragma("unroll") \
    for (int jj = 0; jj < 4; jj++) \
      vv[jj] = fmaxf(ACCV[jj] + bS[jj] + dF * bW[jj] + dB * bT[jj], 0.f); \
    *(f32x4*)(out + (size_t)r * HIDDEN + col0 + kq * 4) = vv; \
  } }
__global__ __launch_bounds__(512, 6) void fused_gather_gemm(
    const short* __restrict__ h_bf, const unsigned* __restrict__ ELP,
    const int* __restrict__ gcur, const short* __restrict__ Wbf,
    const float* __restrict__ Wb, const float* __restrict__ Wsb,
    const float* __restrict__ Wtb, float* __restrict__ out) {
  __shared__ int sorted[BCAP];        // 8 KB
  __shared__ int cnt[128];
  __shared__ int pfx[128];
  __shared__ int cur[128];
  __shared__ short Ht[64 * 128];      // 16 KB swizzled h tile
  __shared__ short At[64 * 128];      // 16 KB swizzled agg tile (reused F/B)
  int tid = threadIdx.x;
  int blk = blockIdx.x;
  int node0 = blk * BKN;
  const unsigned* elp = ELP + (size_t)blk * BCAP;
  int n = min(gcur[blk], BCAP);
  if (tid < 128) cnt[tid] = 0;
  __syncthreads();
  for (int k = tid; k < n; k += 512) atomicAdd(&cnt[elp[k] >> 17], 1);
  // stage h tile (independent of cnt; overlaps histogram latency).
  // row r, chunk c stored at c ^ (r&7)
  for (int p = tid; p < 1024; p += 512) {
    int row = p >> 4, c = p & 15;
    int nd = node0 + row;
    bf16x8 hv = {0, 0, 0, 0, 0, 0, 0, 0};
    if (nd < NN) hv = *(const bf16x8*)(h_bf + (size_t)nd * HIDDEN + c * 8);
    *(bf16x8*)(Ht + row * 128 + ((c ^ (row & 7)) * 8)) = hv;
  }
  __syncthreads();
  // inclusive scan of cnt -> pfx
  int v = (tid < 128) ? cnt[tid] : 0;
  if (tid < 128) pfx[tid] = v;
  __syncthreads();
  for (int off = 1; off < 128; off <<= 1) {
    int add = (tid < 128 && tid >= off) ? pfx[tid - off] : 0;
    __syncthreads();
    if (tid < 128) pfx[tid] += add;
    __syncthreads();
  }
  if (tid < 128) cur[tid] = pfx[tid] - cnt[tid];   // exclusive start
  __syncthreads();
  // scatter into sorted-by-vn LDS array (store nbr only)
  for (int k = tid; k < n; k += 512) {
    unsigned pv = elp[k];
    int slot = atomicAdd(&cur[pv >> 17], 1);
    sorted[slot] = (int)(pv & 0x1FFFFu);
  }
  __syncthreads();

  int qw = tid >> 4, q = tid & 15;
  const short* hb = h_bf + (size_t)q * 8;      // lane's 16B column slice
  int lane = tid & 63;
  int m16 = lane & 15;
  int kq  = lane >> 4;
  int col0 = (tid >> 6) * 16;
  int key = m16 & 7;                  // == rl&7 for every g (rl = g*16+m16)
  f32x4 acc0 = {0.f, 0.f, 0.f, 0.f};
  f32x4 acc1 = {0.f, 0.f, 0.f, 0.f};
  f32x4 acc2 = {0.f, 0.f, 0.f, 0.f};
  f32x4 acc3 = {0.f, 0.f, 0.f, 0.f};

  // B1: forward direction (vns 0..63) -> At
  GATHER_HALF(0)
  __syncthreads();
  // C1: acc = Ws*h + W*aggF (weights loaded here, L1-hot, not held across B2)
  {
    bf16x8 wfS[4], wfF[4];
#pragma unroll
    for (int t = 0; t < 4; t++) {
      wfS[t] = *(const bf16x8*)(Wbf + 0 * 16384 + (col0 + m16) * 128 + t * 32 + kq * 8);
      wfF[t] = *(const bf16x8*)(Wbf + 1 * 16384 + (col0 + m16) * 128 + t * 32 + kq * 8);
    }
    C1_STEP(0, acc0)
    C1_STEP(1, acc1)
    C1_STEP(2, acc2)
    C1_STEP(3, acc3)
  }
  __syncthreads();               // C1 done reading At
  // B2: backward direction (vns 64..127) -> At (overwrite)
  GATHER_HALF(64)
  __syncthreads();
  // C2: acc += Wt*aggB; epilogue
  {
    bf16x8 wfT[4];
#pragma unroll
    for (int t = 0; t < 4; t++)
      wfT[t] = *(const bf16x8*)(Wbf + 2 * 16384 + (col0 + m16) * 128 + t * 32 + kq * 8);
    f32x4 bW = *(const f32x4*)(Wb  + col0 + kq * 4);
    f32x4 bS = *(const f32x4*)(Wsb + col0 + kq * 4);
    f32x4 bT = *(const f32x4*)(Wtb + col0 + kq * 4);
    C2_STEP(0, acc0)
    C2_STEP(1, acc1)
    C2_STEP(2, acc2)
    C2_STEP(3, acc3)
  }
}

extern "C" void kernel_launch(void* const* d_in, const int* in_sizes, int n_in,
                              void* d_out, int out_size, void* d_ws, size_t ws_size,
                              hipStream_t stream) {
  const float* h    = (const float*)d_in[0];
  const int*   esrc = (const int*)d_in[1];
  const int*   edst = (const int*)d_in[2];
  const float* Ww   = (const float*)d_in[3];
  const float* Wb   = (const float*)d_in[4];
  const float* Wsw  = (const float*)d_in[5];
  const float* Wsb  = (const float*)d_in[6];
  const float* Wtw  = (const float*)d_in[7];
  const float* Wtb  = (const float*)d_in[8];
  float* out = (float*)d_out;

  char* ws = (char*)d_ws;
  // byte layout
  int*      gcur = (int*)(ws + 0);              //      6,252
  unsigned* ELP  = (unsigned*)(ws + 6400);      // 12,804,096 (ends 12,810,496)
  short*    Wbf  = (short*)(ws + 12810496);     //     98,304 (ends 12,908,800)
  short*    h_bf = (short*)(ws + 12908800);     // 25,600,000 -> total ~38.5 MB

  hipMemsetAsync(gcur, 0, NBF * sizeof(int), stream);

  convert_all<<<12692, 256, 0, stream>>>(h, Wsw, Ww, Wtw, h_bf, Wbf);
  edge_scatter<<<PBLK, 256, 0, stream>>>(esrc, edst, gcur, ELP);
  fused_gather_gemm<<<NBF, 512, 0, stream>>>(
      h_bf, ELP, gcur, Wbf, Wb, Wsb, Wtb, out);
}

// Round 14
// 254.517 us; speedup vs baseline: 1.0024x; 1.0024x over previous
//
#include <hip/hip_runtime.h>
#include <hip/hip_bf16.h>

#define NN 100000
#define NE 800000
#define HIDDEN 128
#define NED (2 * NE)            // edge-directions: [0,NE)=fwd(by src), [NE,2NE)=bwd(by dst)
#define BKN 64                  // nodes per bucket (bucket covers BOTH directions)
#define NBF 1563                // ceil(NN/BKN)
#define BCAP 2048               // slots per bucket (mean 1024, +32 sigma)
#define PS 7                    // buckets per thread in scatter scan (7*256>=1563)
#define CHUNK 8192              // edges per scatter block (67KB LDS -> 2 blocks/CU)
#define PBLK ((NED + CHUNK - 1) / CHUNK)   // 196

typedef __attribute__((ext_vector_type(8))) short bf16x8;
typedef __attribute__((ext_vector_type(4))) short bf16x4;
typedef __attribute__((ext_vector_type(4))) float f32x4;

__device__ __forceinline__ short f2bf(float f) {
  union { float f; unsigned u; } x; x.f = f;
  unsigned r = x.u + 0x7fffu + ((x.u >> 16) & 1u);   // RNE
  return (short)(r >> 16);
}
__device__ __forceinline__ float bf2f(short s) {
  union { unsigned u; float f; } x;
  x.u = ((unsigned)(unsigned short)s) << 16;
  return x.f;
}

// ---- 1. convert h (12500 blocks) + weights (192 blocks) in ONE kernel ----
// weights order: [0]=Ws_w, [1]=W_w, [2]=Wt_w
__global__ __launch_bounds__(256) void convert_all(
    const float* __restrict__ h, const float* __restrict__ m0,
    const float* __restrict__ m1, const float* __restrict__ m2,
    short* __restrict__ h_bf, short* __restrict__ Wbf) {
  int blk = blockIdx.x;
  int tid = threadIdx.x;
  if (blk < 12500) {
    int i = blk * 256 + tid;                 // 3.2M exact (NN*HIDDEN/4)
    f32x4 v = *(const f32x4*)(h + (size_t)i * 4);
    bf16x4 o;
#pragma unroll
    for (int j = 0; j < 4; j++) o[j] = f2bf(v[j]);
    *(bf16x4*)(h_bf + (size_t)i * 4) = o;
  } else {
    int i = (blk - 12500) * 256 + tid;       // [0, 3*16384) exact
    int m = i >> 14, j = i & 16383;
    const float* s = (m == 0) ? m0 : (m == 1) ? m1 : m2;
    Wbf[i] = f2bf(s[j]);
  }
}

// ---- 2. blocked LDS-aggregated scatter into capacity-allocated regions ----
// LDS count -> LDS scan -> ONE returning atomic per non-empty bucket per
// block -> LDS-staged scatter -> coalesced run sweep.
// ELP item: (dir<<23)|(tl<<17)|nbr; vn=pv>>17. gcur[b] ends as bucket count.
__global__ __launch_bounds__(256) void edge_scatter(
    const int* __restrict__ esrc, const int* __restrict__ edst,
    int* __restrict__ gcur, unsigned* __restrict__ ELP) {
  __shared__ int lcur[NBF];       // counts, then mutable scatter cursors
  __shared__ int loff[NBF];       // block-local exclusive offsets (kept intact)
  __shared__ int gbase[NBF];      // claimed global run starts
  __shared__ int psum[256];
  __shared__ unsigned buf[CHUNK]; // 32 KB staging
  __shared__ unsigned short bidA[CHUNK];  // 16 KB bucket-id per slot
  int tid = threadIdx.x;
  for (int i = tid; i < NBF; i += 256) lcur[i] = 0;
  __syncthreads();
  int base = blockIdx.x * CHUNK;
  int nit = min(CHUNK, NED - base);
  // pass 1: local count
  for (int k = tid; k < nit; k += 256) {
    int ed = base + k;
    int b = (ed < NE) ? (esrc[ed] >> 6) : (edst[ed - NE] >> 6);
    atomicAdd(&lcur[b], 1);
  }
  __syncthreads();
  // local exclusive scan (PS buckets per thread)
  int s = 0;
  int lo0 = tid * PS, hi0 = min(NBF, tid * PS + PS);
  for (int j = lo0; j < hi0; j++) s += lcur[j];
  psum[tid] = s;
  __syncthreads();
  for (int off = 1; off < 256; off <<= 1) {
    int x = psum[tid];
    int add = (tid >= off) ? psum[tid - off] : 0;
    __syncthreads();
    psum[tid] = x + add;
    __syncthreads();
  }
  int run = psum[tid] - s;
  for (int j = lo0; j < hi0; j++) { loff[j] = run; run += lcur[j]; }
  __syncthreads();
  // claim global runs (one returning atomic per non-empty bucket) + cursors
  for (int b = tid; b < NBF; b += 256) {
    int c = lcur[b];
    if (c) gbase[b] = atomicAdd(gcur + b, c);
    lcur[b] = loff[b];
  }
  __syncthreads();
  // pass 2: scatter into LDS staging, record bucket id per slot
  for (int k = tid; k < nit; k += 256) {
    int ed = base + k;
    int b, tl, nbr, dir;
    if (ed < NE) { int tg = esrc[ed]; nbr = edst[ed]; b = tg >> 6; tl = tg & 63; dir = 0; }
    else { int e2 = ed - NE; int tg = edst[e2]; nbr = esrc[e2]; b = tg >> 6; tl = tg & 63; dir = 1; }
    int slot = atomicAdd(&lcur[b], 1);
    buf[slot] = ((unsigned)dir << 23) | ((unsigned)tl << 17) | (unsigned)nbr;
    bidA[slot] = (unsigned short)b;
  }
  __syncthreads();
  // sweep: consecutive lanes -> consecutive slots -> bucket-contiguous runs
  for (int i = tid; i < nit; i += 256) {
    int b = bidA[i];
    int dst = gbase[b] + (i - loff[b]);
    if (dst < BCAP) ELP[(size_t)b * BCAP + dst] = buf[i];
  }
}

// ---- 3. FUSED gather + GEMM per 64-node range, TWO-PASS agg tile ----
// r13 post-mortem: the UNROLLED t<2 vn-loop in the gather let the scheduler
// interleave TWO 4-deep load pipelines (+~40 co-live VGPRs on top of held
// acc) -> pressure > 85 cap -> mass spill (WRITE 119MB). Fix: unroll 1 on
// that loop (serial vns, one pipeline live). Pressure est. ~72 < 85 ->
// no spill, 3 blocks/CU retained.
// B1(gather fwd)->C1(acc=Ws*h+W*aggF)->B2(gather bwd)->C2(acc+=Wt*aggB).
#define ACC8(V) { a0f+=bf2f((V)[0]); a1f+=bf2f((V)[1]); a2f+=bf2f((V)[2]); a3f+=bf2f((V)[3]); \
                  a4f+=bf2f((V)[4]); a5f+=bf2f((V)[5]); a6f+=bf2f((V)[6]); a7f+=bf2f((V)[7]); }
#define MACC8(M,V) { a0f=fmaf(M,bf2f((V)[0]),a0f); a1f=fmaf(M,bf2f((V)[1]),a1f); \
                     a2f=fmaf(M,bf2f((V)[2]),a2f); a3f=fmaf(M,bf2f((V)[3]),a3f); \
                     a4f=fmaf(M,bf2f((V)[4]),a4f); a5f=fmaf(M,bf2f((V)[5]),a5f); \
                     a6f=fmaf(M,bf2f((V)[6]),a6f); a7f=fmaf(M,bf2f((V)[7]),a7f); }
// gather 2 vns of one direction into swizzled At -- SERIAL vns (unroll 1):
// exactly one 4-deep load pipeline live at a time (regalloc fits under 85).
#define GATHER_HALF(VBASE) \
  _Pragma("unroll 1") \
  for (int t = 0; t < 2; t++) { \
    int nd = (VBASE) + qw * 2 + t; \
    int b0 = pfx[nd]; \
    int deg = cnt[nd]; \
    int a0 = b0 - deg; \
    float a0f = 0.f, a1f = 0.f, a2f = 0.f, a3f = 0.f; \
    float a4f = 0.f, a5f = 0.f, a6f = 0.f, a7f = 0.f; \
    if (deg > 0) { \
      int lastp = b0 - 1; \
      int i0 = sorted[a0]; \
      int i1 = sorted[min(a0 + 1, lastp)]; \
      int i2 = sorted[min(a0 + 2, lastp)]; \
      int i3 = sorted[min(a0 + 3, lastp)]; \
      bf16x8 v0 = *(const bf16x8*)(hb + (size_t)i0 * HIDDEN); \
      bf16x8 v1 = *(const bf16x8*)(hb + (size_t)i1 * HIDDEN); \
      bf16x8 v2 = *(const bf16x8*)(hb + (size_t)i2 * HIDDEN); \
      bf16x8 v3 = *(const bf16x8*)(hb + (size_t)i3 * HIDDEN); \
      int j = a0; \
      int ni0 = sorted[min(j + 4, lastp)]; \
      int ni1 = sorted[min(j + 5, lastp)]; \
      int ni2 = sorted[min(j + 6, lastp)]; \
      int ni3 = sorted[min(j + 7, lastp)]; \
      while (j + 4 <= b0) { \
        ACC8(v0); v0 = *(const bf16x8*)(hb + (size_t)ni0 * HIDDEN); \
        ACC8(v1); v1 = *(const bf16x8*)(hb + (size_t)ni1 * HIDDEN); \
        ACC8(v2); v2 = *(const bf16x8*)(hb + (size_t)ni2 * HIDDEN); \
        ACC8(v3); v3 = *(const bf16x8*)(hb + (size_t)ni3 * HIDDEN); \
        j += 4; \
        ni0 = sorted[min(j + 4, lastp)]; \
        ni1 = sorted[min(j + 5, lastp)]; \
        ni2 = sorted[min(j + 6, lastp)]; \
        ni3 = sorted[min(j + 7, lastp)]; \
      } \
      int rrem = b0 - j; \
      float m1 = (rrem > 0) ? 1.f : 0.f; \
      float m2 = (rrem > 1) ? 1.f : 0.f; \
      float m3 = (rrem > 2) ? 1.f : 0.f; \
      MACC8(m1, v0); MACC8(m2, v1); MACC8(m3, v2); \
    } \
    short* dst = At + (nd & 63) * 128 + ((q ^ (nd & 7)) * 8); \
    bf16x8 o; \
    o[0] = f2bf(a0f); o[1] = f2bf(a1f); o[2] = f2bf(a2f); o[3] = f2bf(a3f); \
    o[4] = f2bf(a4f); o[5] = f2bf(a5f); o[6] = f2bf(a6f); o[7] = f2bf(a7f); \
    *(bf16x8*)dst = o; \
  }
// one 16-row group of C1: 4 Ws*h + 4 W*aggF MFMAs into ACCV
#define C1_STEP(G, ACCV) { \
  int rl = (G) * 16 + m16; \
  const short* hrow = Ht + rl * 128; \
  const short* arow = At + rl * 128; \
  _Pragma("unroll") \
  for (int t = 0; t < 4; t++) { \
    int pc = (kq + 4 * t) ^ key; \
    bf16x8 hv = *(const bf16x8*)(hrow + pc * 8); \
    ACCV = __builtin_amdgcn_mfma_f32_16x16x32_bf16(wfS[t], hv, ACCV, 0, 0, 0); \
  } \
  _Pragma("unroll") \
  for (int t = 0; t < 4; t++) { \
    int pc = (kq + 4 * t) ^ key; \
    bf16x8 av = *(const bf16x8*)(arow + pc * 8); \
    ACCV = __builtin_amdgcn_mfma_f32_16x16x32_bf16(wfF[t], av, ACCV, 0, 0, 0); \
  } }
// one 16-row group of C2: 4 Wt*aggB MFMAs + epilogue store
#define C2_STEP(G, ACCV) { \
  int rl = (G) * 16 + m16; \
  const short* arow = At + rl * 128; \
  _Pragma("unroll") \
  for (int t = 0; t < 4; t++) { \
    int pc = (kq + 4 * t) ^ key; \
    bf16x8 av = *(const bf16x8*)(arow + pc * 8); \
    ACCV = __builtin_amdgcn_mfma_f32_16x16x32_bf16(wfT[t], av, ACCV, 0, 0, 0); \
  } \
  int r = node0 + rl; \
  if (r < NN) { \
    float dF = (float)cnt[rl]; \
    float dB = (float)cnt[64 + rl]; \
    f32x4 vv; \
    _Pragma("unroll") \
    for (int jj = 0; jj < 4; jj++) \
      vv[jj] = fmaxf(ACCV[jj] + bS[jj] + dF * bW[jj] + dB * bT[jj], 0.f); \
    *(f32x4*)(out + (size_t)r * HIDDEN + col0 + kq * 4) = vv; \
  } }
__global__ __launch_bounds__(512, 6) void fused_gather_gemm(
    const short* __restrict__ h_bf, const unsigned* __restrict__ ELP,
    const int* __restrict__ gcur, const short* __restrict__ Wbf,
    const float* __restrict__ Wb, const float* __restrict__ Wsb,
    const float* __restrict__ Wtb, float* __restrict__ out) {
  __shared__ int sorted[BCAP];        // 8 KB
  __shared__ int cnt[128];
  __shared__ int pfx[128];
  __shared__ int cur[128];
  __shared__ short Ht[64 * 128];      // 16 KB swizzled h tile
  __shared__ short At[64 * 128];      // 16 KB swizzled agg tile (reused F/B)
  int tid = threadIdx.x;
  int blk = blockIdx.x;
  int node0 = blk * BKN;
  const unsigned* elp = ELP + (size_t)blk * BCAP;
  int n = min(gcur[blk], BCAP);
  if (tid < 128) cnt[tid] = 0;
  __syncthreads();
  for (int k = tid; k < n; k += 512) atomicAdd(&cnt[elp[k] >> 17], 1);
  // stage h tile (independent of cnt; overlaps histogram latency).
  // row r, chunk c stored at c ^ (r&7)
  for (int p = tid; p < 1024; p += 512) {
    int row = p >> 4, c = p & 15;
    int nd = node0 + row;
    bf16x8 hv = {0, 0, 0, 0, 0, 0, 0, 0};
    if (nd < NN) hv = *(const bf16x8*)(h_bf + (size_t)nd * HIDDEN + c * 8);
    *(bf16x8*)(Ht + row * 128 + ((c ^ (row & 7)) * 8)) = hv;
  }
  __syncthreads();
  // inclusive scan of cnt -> pfx
  int v = (tid < 128) ? cnt[tid] : 0;
  if (tid < 128) pfx[tid] = v;
  __syncthreads();
  for (int off = 1; off < 128; off <<= 1) {
    int add = (tid < 128 && tid >= off) ? pfx[tid - off] : 0;
    __syncthreads();
    if (tid < 128) pfx[tid] += add;
    __syncthreads();
  }
  if (tid < 128) cur[tid] = pfx[tid] - cnt[tid];   // exclusive start
  __syncthreads();
  // scatter into sorted-by-vn LDS array (store nbr only)
  for (int k = tid; k < n; k += 512) {
    unsigned pv = elp[k];
    int slot = atomicAdd(&cur[pv >> 17], 1);
    sorted[slot] = (int)(pv & 0x1FFFFu);
  }
  __syncthreads();

  int qw = tid >> 4, q = tid & 15;
  const short* hb = h_bf + (size_t)q * 8;      // lane's 16B column slice
  int lane = tid & 63;
  int m16 = lane & 15;
  int kq  = lane >> 4;
  int col0 = (tid >> 6) * 16;
  int key = m16 & 7;                  // == rl&7 for every g (rl = g*16+m16)
  f32x4 acc0 = {0.f, 0.f, 0.f, 0.f};
  f32x4 acc1 = {0.f, 0.f, 0.f, 0.f};
  f32x4 acc2 = {0.f, 0.f, 0.f, 0.f};
  f32x4 acc3 = {0.f, 0.f, 0.f, 0.f};

  // B1: forward direction (vns 0..63) -> At
  GATHER_HALF(0)
  __syncthreads();
  // C1: acc = Ws*h + W*aggF (weights loaded here, L1-hot, not held across B2)
  {
    bf16x8 wfS[4], wfF[4];
#pragma unroll
    for (int t = 0; t < 4; t++) {
      wfS[t] = *(const bf16x8*)(Wbf + 0 * 16384 + (col0 + m16) * 128 + t * 32 + kq * 8);
      wfF[t] = *(const bf16x8*)(Wbf + 1 * 16384 + (col0 + m16) * 128 + t * 32 + kq * 8);
    }
    C1_STEP(0, acc0)
    C1_STEP(1, acc1)
    C1_STEP(2, acc2)
    C1_STEP(3, acc3)
  }
  __syncthreads();               // C1 done reading At
  // B2: backward direction (vns 64..127) -> At (overwrite)
  GATHER_HALF(64)
  __syncthreads();
  // C2: acc += Wt*aggB; epilogue
  {
    bf16x8 wfT[4];
#pragma unroll
    for (int t = 0; t < 4; t++)
      wfT[t] = *(const bf16x8*)(Wbf + 2 * 16384 + (col0 + m16) * 128 + t * 32 + kq * 8);
    f32x4 bW = *(const f32x4*)(Wb  + col0 + kq * 4);
    f32x4 bS = *(const f32x4*)(Wsb + col0 + kq * 4);
    f32x4 bT = *(const f32x4*)(Wtb + col0 + kq * 4);
    C2_STEP(0, acc0)
    C2_STEP(1, acc1)
    C2_STEP(2, acc2)
    C2_STEP(3, acc3)
  }
}

extern "C" void kernel_launch(void* const* d_in, const int* in_sizes, int n_in,
                              void* d_out, int out_size, void* d_ws, size_t ws_size,
                              hipStream_t stream) {
  const float* h    = (const float*)d_in[0];
  const int*   esrc = (const int*)d_in[1];
  const int*   edst = (const int*)d_in[2];
  const float* Ww   = (const float*)d_in[3];
  const float* Wb   = (const float*)d_in[4];
  const float* Wsw  = (const float*)d_in[5];
  const float* Wsb  = (const float*)d_in[6];
  const float* Wtw  = (const float*)d_in[7];
  const float* Wtb  = (const float*)d_in[8];
  float* out = (float*)d_out;

  char* ws = (char*)d_ws;
  // byte layout
  int*      gcur = (int*)(ws + 0);              //      6,252
  unsigned* ELP  = (unsigned*)(ws + 6400);      // 12,804,096 (ends 12,810,496)
  short*    Wbf  = (short*)(ws + 12810496);     //     98,304 (ends 12,908,800)
  short*    h_bf = (short*)(ws + 12908800);     // 25,600,000 -> total ~38.5 MB

  hipMemsetAsync(gcur, 0, NBF * sizeof(int), stream);

  convert_all<<<12692, 256, 0, stream>>>(h, Wsw, Ww, Wtw, h_bf, Wbf);
  edge_scatter<<<PBLK, 256, 0, stream>>>(esrc, edst, gcur, ELP);
  fused_gather_gemm<<<NBF, 512, 0, stream>>>(
      h_bf, ELP, gcur, Wbf, Wb, Wsb, Wtb, out);
}

// Round 15
// 244.889 us; speedup vs baseline: 1.0419x; 1.0393x over previous
//
#include <hip/hip_runtime.h>
#include <hip/hip_bf16.h>

#define NN 100000
#define NE 800000
#define HIDDEN 128
#define NED (2 * NE)            // edge-directions: [0,NE)=fwd(by src), [NE,2NE)=bwd(by dst)
#define BKN 64                  // nodes per bucket (bucket covers BOTH directions)
#define NBF 1563                // ceil(NN/BKN)
#define BCAP 2048               // slots per bucket (mean 1024, +32 sigma)
#define PS 7                    // buckets per thread in scatter scan (7*256>=1563)
#define CHUNK 8192              // edges per scatter block (67KB LDS -> 2 blocks/CU)
#define PBLK ((NED + CHUNK - 1) / CHUNK)   // 196

typedef __attribute__((ext_vector_type(8))) short bf16x8;
typedef __attribute__((ext_vector_type(4))) short bf16x4;
typedef __attribute__((ext_vector_type(4))) float f32x4;

__device__ __forceinline__ short f2bf(float f) {
  union { float f; unsigned u; } x; x.f = f;
  unsigned r = x.u + 0x7fffu + ((x.u >> 16) & 1u);   // RNE
  return (short)(r >> 16);
}
__device__ __forceinline__ float bf2f(short s) {
  union { unsigned u; float f; } x;
  x.u = ((unsigned)(unsigned short)s) << 16;
  return x.f;
}

// ---- 1. convert h (12500 blocks) + weights (192 blocks) in ONE kernel ----
// weights order: [0]=Ws_w, [1]=W_w, [2]=Wt_w
__global__ __launch_bounds__(256) void convert_all(
    const float* __restrict__ h, const float* __restrict__ m0,
    const float* __restrict__ m1, const float* __restrict__ m2,
    short* __restrict__ h_bf, short* __restrict__ Wbf) {
  int blk = blockIdx.x;
  int tid = threadIdx.x;
  if (blk < 12500) {
    int i = blk * 256 + tid;                 // 3.2M exact (NN*HIDDEN/4)
    f32x4 v = *(const f32x4*)(h + (size_t)i * 4);
    bf16x4 o;
#pragma unroll
    for (int j = 0; j < 4; j++) o[j] = f2bf(v[j]);
    *(bf16x4*)(h_bf + (size_t)i * 4) = o;
  } else {
    int i = (blk - 12500) * 256 + tid;       // [0, 3*16384) exact
    int m = i >> 14, j = i & 16383;
    const float* s = (m == 0) ? m0 : (m == 1) ? m1 : m2;
    Wbf[i] = f2bf(s[j]);
  }
}

// ---- 2. blocked LDS-aggregated scatter into capacity-allocated regions ----
// LDS count -> LDS scan -> ONE returning atomic per non-empty bucket per
// block -> LDS-staged scatter -> coalesced run sweep.
// ELP item: (dir<<23)|(tl<<17)|nbr; vn=pv>>17. gcur[b] ends as bucket count.
__global__ __launch_bounds__(256) void edge_scatter(
    const int* __restrict__ esrc, const int* __restrict__ edst,
    int* __restrict__ gcur, unsigned* __restrict__ ELP) {
  __shared__ int lcur[NBF];       // counts, then mutable scatter cursors
  __shared__ int loff[NBF];       // block-local exclusive offsets (kept intact)
  __shared__ int gbase[NBF];      // claimed global run starts
  __shared__ int psum[256];
  __shared__ unsigned buf[CHUNK]; // 32 KB staging
  __shared__ unsigned short bidA[CHUNK];  // 16 KB bucket-id per slot
  int tid = threadIdx.x;
  for (int i = tid; i < NBF; i += 256) lcur[i] = 0;
  __syncthreads();
  int base = blockIdx.x * CHUNK;
  int nit = min(CHUNK, NED - base);
  // pass 1: local count
  for (int k = tid; k < nit; k += 256) {
    int ed = base + k;
    int b = (ed < NE) ? (esrc[ed] >> 6) : (edst[ed - NE] >> 6);
    atomicAdd(&lcur[b], 1);
  }
  __syncthreads();
  // local exclusive scan (PS buckets per thread)
  int s = 0;
  int lo0 = tid * PS, hi0 = min(NBF, tid * PS + PS);
  for (int j = lo0; j < hi0; j++) s += lcur[j];
  psum[tid] = s;
  __syncthreads();
  for (int off = 1; off < 256; off <<= 1) {
    int x = psum[tid];
    int add = (tid >= off) ? psum[tid - off] : 0;
    __syncthreads();
    psum[tid] = x + add;
    __syncthreads();
  }
  int run = psum[tid] - s;
  for (int j = lo0; j < hi0; j++) { loff[j] = run; run += lcur[j]; }
  __syncthreads();
  // claim global runs (one returning atomic per non-empty bucket) + cursors
  for (int b = tid; b < NBF; b += 256) {
    int c = lcur[b];
    if (c) gbase[b] = atomicAdd(gcur + b, c);
    lcur[b] = loff[b];
  }
  __syncthreads();
  // pass 2: scatter into LDS staging, record bucket id per slot
  for (int k = tid; k < nit; k += 256) {
    int ed = base + k;
    int b, tl, nbr, dir;
    if (ed < NE) { int tg = esrc[ed]; nbr = edst[ed]; b = tg >> 6; tl = tg & 63; dir = 0; }
    else { int e2 = ed - NE; int tg = edst[e2]; nbr = esrc[e2]; b = tg >> 6; tl = tg & 63; dir = 1; }
    int slot = atomicAdd(&lcur[b], 1);
    buf[slot] = ((unsigned)dir << 23) | ((unsigned)tl << 17) | (unsigned)nbr;
    bidA[slot] = (unsigned short)b;
  }
  __syncthreads();
  // sweep: consecutive lanes -> consecutive slots -> bucket-contiguous runs
  for (int i = tid; i < nit; i += 256) {
    int b = bidA[i];
    int dst = gbase[b] + (i - loff[b]);
    if (dst < BCAP) ELP[(size_t)b * BCAP + dst] = buf[i];
  }
}

// ---- 3. FUSED gather + GEMM per 64-node range, TWO-PASS agg tile ----
// [r12 revert — measured best: fused 99.9us, total 246.7us]
// One 16KB At tile reused for both directions:
// B1(gather fwd)->C1(acc=Ws*h+W*aggF, acc in 16 VGPRs)->B2(gather bwd,
// overwrite At)->C2(acc+=Wt*aggB, epilogue).
// LDS 42.5KB -> 3 blocks/CU (50% occ measured). The lambda's modest acc
// spill (~31MB WRITE) is the least-bad variant: flattening it (r13/r14)
// spilled MORE (112-119MB) — compiler regalloc behavior, not steerable
// further from source.
__global__ __launch_bounds__(512, 6) void fused_gather_gemm(
    const short* __restrict__ h_bf, const unsigned* __restrict__ ELP,
    const int* __restrict__ gcur, const short* __restrict__ Wbf,
    const float* __restrict__ Wb, const float* __restrict__ Wsb,
    const float* __restrict__ Wtb, float* __restrict__ out) {
  __shared__ int sorted[BCAP];        // 8 KB
  __shared__ int cnt[128];
  __shared__ int pfx[128];
  __shared__ int cur[128];
  __shared__ short Ht[64 * 128];      // 16 KB swizzled h tile
  __shared__ short At[64 * 128];      // 16 KB swizzled agg tile (reused F/B)
  int tid = threadIdx.x;
  int blk = blockIdx.x;
  int node0 = blk * BKN;
  const unsigned* elp = ELP + (size_t)blk * BCAP;
  int n = min(gcur[blk], BCAP);
  if (tid < 128) cnt[tid] = 0;
  __syncthreads();
  for (int k = tid; k < n; k += 512) atomicAdd(&cnt[elp[k] >> 17], 1);
  // stage h tile (independent of cnt; overlaps histogram latency).
  // row r, chunk c stored at c ^ (r&7)
  for (int p = tid; p < 1024; p += 512) {
    int row = p >> 4, c = p & 15;
    int nd = node0 + row;
    bf16x8 hv = {0, 0, 0, 0, 0, 0, 0, 0};
    if (nd < NN) hv = *(const bf16x8*)(h_bf + (size_t)nd * HIDDEN + c * 8);
    *(bf16x8*)(Ht + row * 128 + ((c ^ (row & 7)) * 8)) = hv;
  }
  __syncthreads();
  // inclusive scan of cnt -> pfx
  int v = (tid < 128) ? cnt[tid] : 0;
  if (tid < 128) pfx[tid] = v;
  __syncthreads();
  for (int off = 1; off < 128; off <<= 1) {
    int add = (tid < 128 && tid >= off) ? pfx[tid - off] : 0;
    __syncthreads();
    if (tid < 128) pfx[tid] += add;
    __syncthreads();
  }
  if (tid < 128) cur[tid] = pfx[tid] - cnt[tid];   // exclusive start
  __syncthreads();
  // scatter into sorted-by-vn LDS array (store nbr only)
  for (int k = tid; k < n; k += 512) {
    unsigned pv = elp[k];
    int slot = atomicAdd(&cur[pv >> 17], 1);
    sorted[slot] = (int)(pv & 0x1FFFFu);
  }
  __syncthreads();

  int qw = tid >> 4, q = tid & 15;
  const short* hb = h_bf + (size_t)q * 8;      // lane's 16B column slice
  int lane = tid & 63;
  int m16 = lane & 15;
  int kq  = lane >> 4;
  int col0 = (tid >> 6) * 16;
  int key = m16 & 7;                  // == rl&7 for every g (rl = g*16+m16)
  f32x4 acc[4];
#pragma unroll
  for (int g = 0; g < 4; g++) acc[g] = (f32x4){0.f, 0.f, 0.f, 0.f};

  // gather one direction's 64 vns (2 per quarter-wave) into At
  auto gather_half = [&](int vbase) {
#pragma unroll
    for (int t = 0; t < 2; t++) {
      int nd = vbase + qw * 2 + t;
      int b0 = pfx[nd];
      int deg = cnt[nd];
      int a0 = b0 - deg;
      float a0f = 0.f, a1f = 0.f, a2f = 0.f, a3f = 0.f;
      float a4f = 0.f, a5f = 0.f, a6f = 0.f, a7f = 0.f;
      if (deg > 0) {
        int lastp = b0 - 1;
        int i0 = sorted[a0];
        int i1 = sorted[min(a0 + 1, lastp)];
        int i2 = sorted[min(a0 + 2, lastp)];
        int i3 = sorted[min(a0 + 3, lastp)];
        bf16x8 v0 = *(const bf16x8*)(hb + (size_t)i0 * HIDDEN);
        bf16x8 v1 = *(const bf16x8*)(hb + (size_t)i1 * HIDDEN);
        bf16x8 v2 = *(const bf16x8*)(hb + (size_t)i2 * HIDDEN);
        bf16x8 v3 = *(const bf16x8*)(hb + (size_t)i3 * HIDDEN);
        int j = a0;
        int ni0 = sorted[min(j + 4, lastp)];
        int ni1 = sorted[min(j + 5, lastp)];
        int ni2 = sorted[min(j + 6, lastp)];
        int ni3 = sorted[min(j + 7, lastp)];
        while (j + 4 <= b0) {
          float w0 = bf2f(v0[0]);  // (macro-free to keep lambda light)
          a0f += bf2f(v0[0]); a1f += bf2f(v0[1]); a2f += bf2f(v0[2]); a3f += bf2f(v0[3]);
          a4f += bf2f(v0[4]); a5f += bf2f(v0[5]); a6f += bf2f(v0[6]); a7f += bf2f(v0[7]);
          v0 = *(const bf16x8*)(hb + (size_t)ni0 * HIDDEN);
          a0f += bf2f(v1[0]); a1f += bf2f(v1[1]); a2f += bf2f(v1[2]); a3f += bf2f(v1[3]);
          a4f += bf2f(v1[4]); a5f += bf2f(v1[5]); a6f += bf2f(v1[6]); a7f += bf2f(v1[7]);
          v1 = *(const bf16x8*)(hb + (size_t)ni1 * HIDDEN);
          a0f += bf2f(v2[0]); a1f += bf2f(v2[1]); a2f += bf2f(v2[2]); a3f += bf2f(v2[3]);
          a4f += bf2f(v2[4]); a5f += bf2f(v2[5]); a6f += bf2f(v2[6]); a7f += bf2f(v2[7]);
          v2 = *(const bf16x8*)(hb + (size_t)ni2 * HIDDEN);
          a0f += bf2f(v3[0]); a1f += bf2f(v3[1]); a2f += bf2f(v3[2]); a3f += bf2f(v3[3]);
          a4f += bf2f(v3[4]); a5f += bf2f(v3[5]); a6f += bf2f(v3[6]); a7f += bf2f(v3[7]);
          v3 = *(const bf16x8*)(hb + (size_t)ni3 * HIDDEN);
          j += 4;
          ni0 = sorted[min(j + 4, lastp)];
          ni1 = sorted[min(j + 5, lastp)];
          ni2 = sorted[min(j + 6, lastp)];
          ni3 = sorted[min(j + 7, lastp)];
          (void)w0;
        }
        int r = b0 - j;   // 0..3 remaining; v0..v2 hold edges j..j+2 (clamped dups)
        float m1 = (r > 0) ? 1.f : 0.f;
        float m2 = (r > 1) ? 1.f : 0.f;
        float m3 = (r > 2) ? 1.f : 0.f;
        a0f = fmaf(m1, bf2f(v0[0]), a0f); a1f = fmaf(m1, bf2f(v0[1]), a1f);
        a2f = fmaf(m1, bf2f(v0[2]), a2f); a3f = fmaf(m1, bf2f(v0[3]), a3f);
        a4f = fmaf(m1, bf2f(v0[4]), a4f); a5f = fmaf(m1, bf2f(v0[5]), a5f);
        a6f = fmaf(m1, bf2f(v0[6]), a6f); a7f = fmaf(m1, bf2f(v0[7]), a7f);
        a0f = fmaf(m2, bf2f(v1[0]), a0f); a1f = fmaf(m2, bf2f(v1[1]), a1f);
        a2f = fmaf(m2, bf2f(v1[2]), a2f); a3f = fmaf(m2, bf2f(v1[3]), a3f);
        a4f = fmaf(m2, bf2f(v1[4]), a4f); a5f = fmaf(m2, bf2f(v1[5]), a5f);
        a6f = fmaf(m2, bf2f(v1[6]), a6f); a7f = fmaf(m2, bf2f(v1[7]), a7f);
        a0f = fmaf(m3, bf2f(v2[0]), a0f); a1f = fmaf(m3, bf2f(v2[1]), a1f);
        a2f = fmaf(m3, bf2f(v2[2]), a2f); a3f = fmaf(m3, bf2f(v2[3]), a3f);
        a4f = fmaf(m3, bf2f(v2[4]), a4f); a5f = fmaf(m3, bf2f(v2[5]), a5f);
        a6f = fmaf(m3, bf2f(v2[6]), a6f); a7f = fmaf(m3, bf2f(v2[7]), a7f);
      }
      // swizzled write: row = tl = nd&63, chunk q stored at q ^ (row&7)
      short* dst = At + (nd & 63) * 128 + ((q ^ (nd & 7)) * 8);
      bf16x8 o;
      o[0] = f2bf(a0f); o[1] = f2bf(a1f); o[2] = f2bf(a2f); o[3] = f2bf(a3f);
      o[4] = f2bf(a4f); o[5] = f2bf(a5f); o[6] = f2bf(a6f); o[7] = f2bf(a7f);
      *(bf16x8*)dst = o;
    }
  };

  // B1: forward direction (vns 0..63) -> At
  gather_half(0);
  __syncthreads();
  // C1: acc = Ws*h + W*aggF (weights loaded here, L1-hot, not held across B2)
  {
    bf16x8 wfS[4], wfF[4];
#pragma unroll
    for (int t = 0; t < 4; t++) {
      wfS[t] = *(const bf16x8*)(Wbf + 0 * 16384 + (col0 + m16) * 128 + t * 32 + kq * 8);
      wfF[t] = *(const bf16x8*)(Wbf + 1 * 16384 + (col0 + m16) * 128 + t * 32 + kq * 8);
    }
#pragma unroll
    for (int g = 0; g < 4; g++) {
      int rl = g * 16 + m16;
      const short* hrow = Ht + rl * 128;
      const short* arow = At + rl * 128;
#pragma unroll
      for (int t = 0; t < 4; t++) {
        int pc = (kq + 4 * t) ^ key;
        bf16x8 hv = *(const bf16x8*)(hrow + pc * 8);
        acc[g] = __builtin_amdgcn_mfma_f32_16x16x32_bf16(wfS[t], hv, acc[g], 0, 0, 0);
      }
#pragma unroll
      for (int t = 0; t < 4; t++) {
        int pc = (kq + 4 * t) ^ key;
        bf16x8 av = *(const bf16x8*)(arow + pc * 8);
        acc[g] = __builtin_amdgcn_mfma_f32_16x16x32_bf16(wfF[t], av, acc[g], 0, 0, 0);
      }
    }
  }
  __syncthreads();               // C1 done reading At
  // B2: backward direction (vns 64..127) -> At (overwrite)
  gather_half(64);
  __syncthreads();
  // C2: acc += Wt*aggB; epilogue
  {
    bf16x8 wfT[4];
#pragma unroll
    for (int t = 0; t < 4; t++)
      wfT[t] = *(const bf16x8*)(Wbf + 2 * 16384 + (col0 + m16) * 128 + t * 32 + kq * 8);
    f32x4 bW = *(const f32x4*)(Wb  + col0 + kq * 4);
    f32x4 bS = *(const f32x4*)(Wsb + col0 + kq * 4);
    f32x4 bT = *(const f32x4*)(Wtb + col0 + kq * 4);
#pragma unroll
    for (int g = 0; g < 4; g++) {
      int rl = g * 16 + m16;
      const short* arow = At + rl * 128;
#pragma unroll
      for (int t = 0; t < 4; t++) {
        int pc = (kq + 4 * t) ^ key;
        bf16x8 av = *(const bf16x8*)(arow + pc * 8);
        acc[g] = __builtin_amdgcn_mfma_f32_16x16x32_bf16(wfT[t], av, acc[g], 0, 0, 0);
      }
      int r = node0 + rl;
      if (r < NN) {
        float dF = (float)cnt[rl];
        float dB = (float)cnt[64 + rl];
        f32x4 vv;
#pragma unroll
        for (int j = 0; j < 4; j++)
          vv[j] = fmaxf(acc[g][j] + bS[j] + dF * bW[j] + dB * bT[j], 0.f);
        *(f32x4*)(out + (size_t)r * HIDDEN + col0 + kq * 4) = vv;
      }
    }
  }
}

extern "C" void kernel_launch(void* const* d_in, const int* in_sizes, int n_in,
                              void* d_out, int out_size, void* d_ws, size_t ws_size,
                              hipStream_t stream) {
  const float* h    = (const float*)d_in[0];
  const int*   esrc = (const int*)d_in[1];
  const int*   edst = (const int*)d_in[2];
  const float* Ww   = (const float*)d_in[3];
  const float* Wb   = (const float*)d_in[4];
  const float* Wsw  = (const float*)d_in[5];
  const float* Wsb  = (const float*)d_in[6];
  const float* Wtw  = (const float*)d_in[7];
  const float* Wtb  = (const float*)d_in[8];
  float* out = (float*)d_out;

  char* ws = (char*)d_ws;
  // byte layout
  int*      gcur = (int*)(ws + 0);              //      6,252
  unsigned* ELP  = (unsigned*)(ws + 6400);      // 12,804,096 (ends 12,810,496)
  short*    Wbf  = (short*)(ws + 12810496);     //     98,304 (ends 12,908,800)
  short*    h_bf = (short*)(ws + 12908800);     // 25,600,000 -> total ~38.5 MB

  hipMemsetAsync(gcur, 0, NBF * sizeof(int), stream);

  convert_all<<<12692, 256, 0, stream>>>(h, Wsw, Ww, Wtw, h_bf, Wbf);
  edge_scatter<<<PBLK, 256, 0, stream>>>(esrc, edst, gcur, ELP);
  fused_gather_gemm<<<NBF, 512, 0, stream>>>(
      h_bf, ELP, gcur, Wbf, Wb, Wsb, Wtb, out);
}